// Round 5
// baseline (156.451 us; speedup 1.0000x reference)
//
#include <hip/hip_runtime.h>
#include <math.h>

// Problem dims
#define BSZ_ 8
#define LEN_ 8192
#define NC_  128          // scan chunks per sequence
#define CT_  64           // chunk length

typedef __attribute__((ext_vector_type(8))) short bf16x8;
typedef __attribute__((ext_vector_type(4))) float f32x4;
typedef unsigned long long ulong64;

// Workspace layout (float offsets).
#define OFF_PRM 0                                   // 128*16 per-p scalars
#define OFF_W1T 2048                                // bf16 [256][128]  (W1^T: [pc][h])
#define OFF_W2T (OFF_W1T + 16384)                   // bf16 [128][256]  (W2^T: [h][pc])
#define OFF_MPW (OFF_W2T + 16384)                   // float2 [65][128]: (m21,m22) of M^k, k-major
#define OFF_LOC (OFF_MPW + 16640)                   // ulong64 [1024][256]: chunk-local summaries
#define OFF_INC (OFF_LOC + 2 * 1024 * 256)          // ulong64 [1024][256]: inclusive prefixes
#define OFF_CNT (OFF_INC + 2 * 1024 * 256)          // u32 virtual-block counter

#define POISON64 0x7FF0BEEF7FF0BEEFull              // NaN|NaN: "not yet published"

__device__ __forceinline__ unsigned short f2bf(float f) {
    unsigned u = __builtin_bit_cast(unsigned, f);
    u += 0x7fffu + ((u >> 16) & 1u);               // round-to-nearest-even
    return (unsigned short)(u >> 16);
}

// cheap round-half-up bf16 (differs from RNE only on exact ties): 2 VALU ops
__device__ __forceinline__ unsigned short f2bf_fast(float f) {
    unsigned u = __builtin_bit_cast(unsigned, f);
    return (unsigned short)((u + 0x8000u) >> 16);
}

__device__ __forceinline__ void pub8(ulong64* a, float x, float y) {
    float2 v = make_float2(x, y);
    __hip_atomic_store(a, __builtin_bit_cast(ulong64, v),
                       __ATOMIC_RELAXED, __HIP_MEMORY_SCOPE_AGENT);
}
__device__ __forceinline__ ulong64 rd8(const ulong64* a) {
    return __hip_atomic_load((ulong64*)a, __ATOMIC_RELAXED, __HIP_MEMORY_SCOPE_AGENT);
}

// ---------------------------------------------------------------------------
// Setup: weight conversion + per-p scalars + M-power table + poison-init of
// the lookback arrays + counter reset.  grid = 128 x 256
// ---------------------------------------------------------------------------
__global__ __launch_bounds__(256) void k_setup(const float* __restrict__ A_diag,
                                               const float* __restrict__ G_diag,
                                               const float* __restrict__ dt,
                                               const float* __restrict__ B,
                                               const float* __restrict__ C,
                                               float* __restrict__ ws)
{
    int i = blockIdx.x * 256 + threadIdx.x;        // 0..32767
    // W1T[pc][h] = c1[p] * B[p,h,c]
    {
        int pc = i >> 7, h = i & 127;
        int p = pc >> 1, cc = pc & 1;
        float dts = 1.f / (1.f + expf(-dt[p]));
        float G = fmaxf(G_diag[p], 0.f);
        float c1 = dts / (1.f + dts * G);
        ((unsigned short*)(ws + OFF_W1T))[i] = f2bf(c1 * B[p * 256 + h * 2 + cc]);
    }
    // W2T[h][pc] = +Cr / -Ci ; C layout is exactly linear in i
    {
        float v = C[i];
        ((unsigned short*)(ws + OFF_W2T))[i] = f2bf((i & 1) ? -v : v);
    }
    // poison lookback arrays: LOC and INC are contiguous, 524288 ulong64 total
    {
        ulong64* L = (ulong64*)(ws + OFF_LOC);
#pragma unroll
        for (int k = 0; k < 16; ++k) L[(size_t)k * 32768 + i] = POISON64;
    }
    if (i == 0) *(unsigned*)(ws + OFF_CNT) = 0u;

    // M-power table, fully parallel: threads 0..8191 -> (k = 1..64, p = 0..127)
    if (i < 8192) {
        int k = (i >> 7) + 1;                      // 1..64
        int p = i & 127;
        float dtv = dt[p];
        float dts = 1.f / (1.f + expf(-dtv));
        float A   = fmaxf(A_diag[p], 0.f);
        float G   = fmaxf(G_diag[p], 0.f);
        float dt2 = fmaxf(dts * dts, 1e-6f);
        float s   = sqrtf(1.f + dts * G);
        float A_low  = (2.f + dts * G - 2.f * s) / dt2;
        float A_high = (2.f + dts * G + 2.f * s) / dt2;
        float Af = A_low + fmaxf(A - A_low, 0.f) - fmaxf(A - A_high, 0.f);
        float S   = 1.f + dts * G;
        float M11 = 1.f / S;
        float M12 = -(dts / S) * Af;
        float M21 = dts / S;
        float M22 = 1.f - (dts * dts / S) * Af;

        // R = M^k via binary exponentiation (powers of M commute)
        float r11 = 1.f, r12 = 0.f, r21 = 0.f, r22 = 1.f;
        float b11 = M11, b12 = M12, b21 = M21, b22 = M22;
        int kk = k;
#pragma unroll
        for (int it = 0; it < 7; ++it) {
            if (kk & 1) {
                float t11 = b11 * r11 + b12 * r21;
                float t12 = b11 * r12 + b12 * r22;
                float t21 = b21 * r11 + b22 * r21;
                float t22 = b21 * r12 + b22 * r22;
                r11 = t11; r12 = t12; r21 = t21; r22 = t22;
            }
            float s11 = b11 * b11 + b12 * b21;
            float s12 = b11 * b12 + b12 * b22;
            float s21 = b21 * b11 + b22 * b21;
            float s22 = b21 * b12 + b22 * b22;
            b11 = s11; b12 = s12; b21 = s21; b22 = s22;
            kk >>= 1;
        }
        // k-major table: MPW[k][p] = (m21,m22) of M^k
        float2* MPW = (float2*)(ws + OFF_MPW);
        MPW[k * 128 + p] = make_float2(r21, r22);

        float* prm = ws + OFF_PRM + p * 16;
        if (k == 1) {
            prm[0] = M11; prm[1] = M12; prm[2] = M21; prm[3] = M22; prm[4] = dts;
        }
        if (k == 64) {                              // T = M^64 (chunk step)
            prm[5] = r11; prm[6] = r12; prm[7] = r21; prm[8] = r22;
        }
    }
}

// ---------------------------------------------------------------------------
// Shared device pieces
// ---------------------------------------------------------------------------
__device__ __forceinline__ void stage_x(const float* __restrict__ X, size_t row0,
                                        int tid, unsigned short (*xs)[136])
{
    int r = tid >> 4, cl = (tid & 15) * 8;
#pragma unroll
    for (int i = 0; i < 4; ++i) {
        int rr = r + i * 16;
        const float* src = X + (row0 + rr) * 128 + cl;
        float4 v0 = *(const float4*)src;
        float4 v1 = *(const float4*)(src + 4);
        unsigned short* dst = &xs[rr][cl];
        dst[0] = f2bf_fast(v0.x); dst[1] = f2bf_fast(v0.y); dst[2] = f2bf_fast(v0.z); dst[3] = f2bf_fast(v0.w);
        dst[4] = f2bf_fast(v1.x); dst[5] = f2bf_fast(v1.y); dst[6] = f2bf_fast(v1.z); dst[7] = f2bf_fast(v1.w);
    }
}

// GEMM1 64x256x128: A = xs (LDS), B-frags straight from global W1T (L2-hot)
__device__ __forceinline__ void gemm1_acc(const unsigned short (*xs)[136],
                                          const unsigned short* __restrict__ W1T,
                                          int wv, int lane, f32x4 acc[4][4])
{
    int l15 = lane & 15, quad = lane >> 4;
    int nbase = wv * 64;
#pragma unroll
    for (int kk = 0; kk < 4; ++kk) {
        int k0 = kk * 32 + quad * 8;
        bf16x8 af[4], bg[4];
#pragma unroll
        for (int mi = 0; mi < 4; ++mi) af[mi] = *(const bf16x8*)&xs[mi * 16 + l15][k0];
#pragma unroll
        for (int nj = 0; nj < 4; ++nj)
            bg[nj] = *(const bf16x8*)(W1T + (size_t)(nbase + nj * 16 + l15) * 128 + k0);
#pragma unroll
        for (int mi = 0; mi < 4; ++mi)
#pragma unroll
            for (int nj = 0; nj < 4; ++nj)
                acc[mi][nj] = __builtin_amdgcn_mfma_f32_16x16x32_bf16(af[mi], bg[nj], acc[mi][nj], 0, 0, 0);
    }
}

// ---------------------------------------------------------------------------
// Fused main kernel: GEMM1 (once, acc in regs) -> wave-local barrier-free
// scan (pass 1: chunk summary) -> decoupled lookback across chunks (value-
// encoded readiness, relaxed agent atomics, schedule-ordered vbids, no
// deadlock) -> pass 2 rescan fused with prefix-apply -> ysb -> GEMM2 + D.*x.
// Barriers per block: 4 (was 10 across two kernels + scan2 + gaps).
// LDS: region1 17408 B (xs, then 4 wave-local fl slices) + ysb 33792 B
//   = 51.2 KB -> 3 blk/CU.  grid = 1024 x 256
// ---------------------------------------------------------------------------
__global__ __launch_bounds__(256, 3) void k_main(const float* __restrict__ X,
                                                 const float* __restrict__ Dv,
                                                 float* __restrict__ ws,
                                                 float* __restrict__ out)
{
    __shared__ __align__(16) char smem1[17408];                 // xs | fl slices
    __shared__ __align__(16) unsigned short ysb[64][264];
    __shared__ int vbs;

    int tid = threadIdx.x;
    if (tid == 0) vbs = (int)atomicAdd((unsigned*)(ws + OFF_CNT), 1u);
    __syncthreads();
    int bid = vbs;                                  // schedule-ordered virtual id
    int b = bid >> 7, c = bid & 127;
    size_t row0 = (size_t)b * LEN_ + (size_t)c * CT_;

    unsigned short (*xs)[136] = (unsigned short (*)[136])smem1;
    stage_x(X, row0, tid, xs);
    __syncthreads();

    int wv = tid >> 6, lane = tid & 63;
    int l15 = lane & 15, quad = lane >> 4;
    f32x4 acc[4][4] = {};
    gemm1_acc(xs, (const unsigned short*)(ws + OFF_W1T), wv, lane, acc);

    const float* prm = ws + OFF_PRM + (tid >> 1) * 16;
    float M11 = prm[0], M12 = prm[1], dts = prm[4];
    float T11 = prm[5], T12 = prm[6], T21 = prm[7], T22 = prm[8];

    __syncthreads();            // xs fully consumed; fl slices may overwrite it

    // wave-local fl slice: [16][68] f32 at byte offset wv*4352 (no barriers)
    float (*fw)[68] = (float (*)[68])(smem1 + wv * 4352);

    // ---- pass 1: chunk-local scan -> summary (h1,h2) per channel ----
    float h1 = 0.f, h2 = 0.f;
#pragma unroll
    for (int q4 = 0; q4 < 4; ++q4) {
#pragma unroll
        for (int nj = 0; nj < 4; ++nj)
#pragma unroll
            for (int r = 0; r < 4; ++r)
                fw[quad * 4 + r][nj * 16 + l15] = acc[q4][nj][r];
#pragma unroll
        for (int t = 0; t < 16; ++t) {
            float u = fw[t][lane];
            float n1 = fmaf(M11, h1, fmaf(M12, h2, u));
            float n2 = fmaf(dts, n1, h2);          // == M21*h1 + M22*h2 + dts*u
            h1 = n1; h2 = n2;
        }
    }

    // ---- publish local summary; resolve prefix via decoupled lookback ----
    ulong64* LOC = (ulong64*)(ws + OFF_LOC);
    ulong64* INC = (ulong64*)(ws + OFF_INC);
    size_t me = (size_t)bid * 256 + tid;
    pub8(&LOC[me], h1, h2);

    float P1 = 0.f, P2 = 0.f;
    if (c == 0) {
        pub8(&INC[me], h1, h2);                    // inclusive == local
    } else {
        size_t rowb = (size_t)(b * NC_) * 256 + tid;
        float W11 = 1.f, W12 = 0.f, W21 = 0.f, W22 = 1.f;   // T^k, k=0
        int j = c - 1;
        while (true) {
            ulong64 vi = rd8(&INC[rowb + (size_t)j * 256]);
            if (vi != POISON64) {                  // inclusive ready: jump+stop
                float2 I = __builtin_bit_cast(float2, vi);
                P1 = fmaf(W11, I.x, fmaf(W12, I.y, P1));
                P2 = fmaf(W21, I.x, fmaf(W22, I.y, P2));
                break;
            }
            ulong64 vl = rd8(&LOC[rowb + (size_t)j * 256]);
            if (vl != POISON64) {                  // absorb local, step back
                float2 s = __builtin_bit_cast(float2, vl);
                P1 = fmaf(W11, s.x, fmaf(W12, s.y, P1));
                P2 = fmaf(W21, s.x, fmaf(W22, s.y, P2));
                float n11 = W11 * T11 + W12 * T21, n12 = W11 * T12 + W12 * T22;
                float n21 = W21 * T11 + W22 * T21, n22 = W21 * T12 + W22 * T22;
                W11 = n11; W12 = n12; W21 = n21; W22 = n22;
                if (--j < 0) break;
            } else {
                __builtin_amdgcn_s_sleep(2);
            }
        }
        // publish inclusive for successors: I_c = T*P + s_c
        float I1 = fmaf(T11, P1, fmaf(T12, P2, h1));
        float I2 = fmaf(T21, P1, fmaf(T22, P2, h2));
        pub8(&INC[me], I1, I2);
    }

    // ---- pass 2: rescan fused with prefix-apply -> ysb (bf16) ----
    const float2* MPW = (const float2*)(ws + OFF_MPW);
    int p = tid >> 1;
    h1 = 0.f; h2 = 0.f;
#pragma unroll
    for (int q4 = 0; q4 < 4; ++q4) {
#pragma unroll
        for (int nj = 0; nj < 4; ++nj)
#pragma unroll
            for (int r = 0; r < 4; ++r)
                fw[quad * 4 + r][nj * 16 + l15] = acc[q4][nj][r];
#pragma unroll
        for (int t = 0; t < 16; ++t) {
            int tt = q4 * 16 + t;
            float u = fw[t][lane];
            float n1 = fmaf(M11, h1, fmaf(M12, h2, u));
            float n2 = fmaf(dts, n1, h2);
            h1 = n1; h2 = n2;
            float2 m = MPW[(tt + 1) * 128 + p];    // (m21,m22) of M^{tt+1}
            float y = fmaf(m.x, P1, fmaf(m.y, P2, n2));
            ysb[tt][tid] = f2bf_fast(y);
        }
    }
    __syncthreads();            // ysb ready for cross-wave GEMM2

    // ---- GEMM2 64x128x256: A = ys (LDS bf16), B-frags from global W2T ----
    int mrow = (wv & 1) * 32, ncol = (wv >> 1) * 64;
    f32x4 a2[2][4] = {};
    const unsigned short* W2T = (const unsigned short*)(ws + OFF_W2T);
#pragma unroll
    for (int kk = 0; kk < 8; ++kk) {
        int k0 = kk * 32 + quad * 8;
        bf16x8 af[2], bg[4];
#pragma unroll
        for (int mi = 0; mi < 2; ++mi) af[mi] = *(const bf16x8*)&ysb[mrow + mi * 16 + l15][k0];
#pragma unroll
        for (int nj = 0; nj < 4; ++nj)
            bg[nj] = *(const bf16x8*)(W2T + (size_t)(ncol + nj * 16 + l15) * 256 + k0);
#pragma unroll
        for (int mi = 0; mi < 2; ++mi)
#pragma unroll
            for (int nj = 0; nj < 4; ++nj)
                a2[mi][nj] = __builtin_amdgcn_mfma_f32_16x16x32_bf16(af[mi], bg[nj], a2[mi][nj], 0, 0, 0);
    }

    // ---- epilogue: out = a2 + D .* x (fp32 exact; X tile is L3-hot) ----
#pragma unroll
    for (int mi = 0; mi < 2; ++mi)
#pragma unroll
        for (int nj = 0; nj < 4; ++nj) {
            int col = ncol + nj * 16 + l15;
            float d = Dv[col];
#pragma unroll
            for (int r = 0; r < 4; ++r) {
                size_t gr = row0 + mrow + mi * 16 + quad * 4 + r;
                float xv = X[gr * 128 + col];
                out[gr * 128 + col] = fmaf(d, xv, a2[mi][nj][r]);
            }
        }
}

// ---------------------------------------------------------------------------
extern "C" void kernel_launch(void* const* d_in, const int* in_sizes, int n_in,
                              void* d_out, int out_size, void* d_ws, size_t ws_size,
                              hipStream_t stream) {
    const float* x      = (const float*)d_in[0];
    const float* A_diag = (const float*)d_in[1];
    const float* G_diag = (const float*)d_in[2];
    const float* dt     = (const float*)d_in[3];
    const float* B      = (const float*)d_in[4];
    const float* C      = (const float*)d_in[5];
    const float* Dv     = (const float*)d_in[6];
    float* out = (float*)d_out;
    float* ws  = (float*)d_ws;

    k_setup<<<128, 256, 0, stream>>>(A_diag, G_diag, dt, B, C, ws);
    k_main<<<BSZ_ * NC_, 256, 0, stream>>>(x, Dv, ws, out);
}